// Round 12
// baseline (720.776 us; speedup 1.0000x reference)
//
#include <hip/hip_runtime.h>

typedef unsigned short u16;
typedef unsigned int   u32;
typedef __attribute__((ext_vector_type(4))) float floatx4;
typedef __attribute__((ext_vector_type(8))) short shortx8;

#define BB 8192
#define SS 18
#define DD 512

// ---------- helpers ----------
__device__ __forceinline__ u16 f2bf(float f){            // RNE f32->bf16
  u32 u = __float_as_uint(f);
  return (u16)((u + 0x7FFFu + ((u >> 16) & 1u)) >> 16);
}
__device__ __forceinline__ float bf2f(u16 x){ return __uint_as_float(((u32)x)<<16); }

__device__ __forceinline__ shortx8 pack8v(floatx4 a, floatx4 b){
  shortx8 t;
  t[0]=(short)f2bf(a[0]); t[1]=(short)f2bf(a[1]); t[2]=(short)f2bf(a[2]); t[3]=(short)f2bf(a[3]);
  t[4]=(short)f2bf(b[0]); t[5]=(short)f2bf(b[1]); t[6]=(short)f2bf(b[2]); t[7]=(short)f2bf(b[3]);
  return t;
}

__device__ __forceinline__ void gload16(const void* g, void* l){
  __builtin_amdgcn_global_load_lds((const __attribute__((address_space(1))) void*)g,
                                   (__attribute__((address_space(3))) void*)l, 16, 0, 0);
}

// 256-thread staging of one [R][64] bf16 chunk (swizzled image), CALLS per wave
template<int CALLS>
__device__ __forceinline__ void gstage(const char* src, size_t rowStrideB, int chunkByteOff,
                                       char* lds, int wid, int lane){
#pragma unroll
  for (int i=0;i<CALLS;++i){
    int base = (wid*CALLS + i)*1024;
    int off  = base + lane*16;
    int row  = off >> 7;
    int blk  = ((off >> 4) & 7) ^ (row & 7);
    gload16(src + (size_t)row*rowStrideB + chunkByteOff + blk*16, lds + base);
  }
}

// 512-thread staging of one [128][64] bf16 chunk: 2 insts/thread
__device__ __forceinline__ void gstage8(const char* src, size_t rowStrideB, int chunkByteOff,
                                        char* lds, int wid, int lane){
#pragma unroll
  for (int i=0;i<2;++i){
    int base = (wid*2 + i)*1024;
    int off  = base + lane*16;
    int row  = off >> 7;
    int blk  = ((off >> 4) & 7) ^ (row & 7);
    gload16(src + (size_t)row*rowStrideB + chunkByteOff + blk*16, lds + base);
  }
}

__device__ __forceinline__ void lds_store4(char* buf, int row, int rowBytes, int khByte,
                                           int swzMask, const shortx8* v){
#pragma unroll
  for (int q=0;q<4;++q){
    int off = row*rowBytes + khByte + q*16;
    off ^= (row & swzMask) << 4;
    *(shortx8*)(buf + off) = v[q];
  }
}

__device__ __forceinline__ void stage_bf16(char* buf, const u16* gsrc, size_t srcRowBytes, int tid){
  int row = tid >> 1, kh = tid & 1;
  const char* p = (const char*)gsrc + (size_t)row*srcRowBytes + kh*64;
  shortx8 v[4];
#pragma unroll
  for (int q=0;q<4;++q) v[q] = *(const shortx8*)(p + q*16);
  lds_store4(buf, row, 128, kh*64, 7, v);
}

__device__ __forceinline__ shortx8 lds_frag(const char* buf, int row, int rowBytes, int kByte,
                                            int swzMask, int lane){
  int off = row*rowBytes + kByte + ((lane>>4)<<4);
  off ^= (row & swzMask) << 4;
  return *(const shortx8*)(buf + off);
}

template<int MF, int NF>
__device__ __forceinline__ void mma64(const char* As, const char* Bs, int wm, int wn, int lane,
                                      floatx4 acc[MF][NF]){
#pragma unroll
  for (int kk=0; kk<2; ++kk){
    shortx8 a[MF], b[NF];
#pragma unroll
    for (int i=0;i<MF;++i) a[i] = lds_frag(As, wm + i*16 + (lane&15), 128, kk*64, 7, lane);
#pragma unroll
    for (int j=0;j<NF;++j) b[j] = lds_frag(Bs, wn + j*16 + (lane&15), 128, kk*64, 7, lane);
#pragma unroll
    for (int i=0;i<MF;++i)
#pragma unroll
      for (int j=0;j<NF;++j)
        acc[i][j] = __builtin_amdgcn_mfma_f32_16x16x32_bf16(a[i], b[j], acc[i][j], 0, 0, 0);
  }
}

// bijective XCD chunking (nwg % 8 == 0)
__device__ __forceinline__ int xcd_swz(int bid, int nwg){
  int q = nwg >> 3;
  return (bid & 7)*q + (bid >> 3);
}

// ---------- prep ----------
__global__ __launch_bounds__(256) void transpose_w2(const float* __restrict__ src,
                                                    u16* __restrict__ dst,
                                                    int sKstride, int kSrcOff, int Kuse,
                                                    int N, int Kpad, int kDstOff){
  __shared__ float tile[32][33];
  int s = blockIdx.z;
  int k0 = blockIdx.x*32, n0 = blockIdx.y*32;
  int tx = threadIdx.x & 31, ty = threadIdx.x >> 5;
#pragma unroll
  for (int r=0;r<4;++r){
    int k = k0 + ty*4 + r;
    float v = (k < Kuse) ? src[((size_t)s*sKstride + kSrcOff + k)*N + n0 + tx] : 0.f;
    tile[ty*4+r][tx] = v;
  }
  __syncthreads();
#pragma unroll
  for (int r=0;r<4;++r){
    int n = n0 + ty*4 + r;
    dst[((size_t)s*N + n)*Kpad + kDstOff + k0 + tx] = f2bf(tile[tx][ty*4+r]);
  }
}

// ---------- bn: h2b + gsb side-write (gsb now (s,m,d) layout) ----------
__global__ __launch_bounds__(256) void k_bn(const float* __restrict__ gs,
     const u16* __restrict__ w1t, const u16* __restrict__ w2t,
     const float* __restrict__ b1, const float* __restrict__ b2,
     u16* __restrict__ h2b, u16* __restrict__ gsb){
  __shared__ __align__(16) char SMB[40960];
  int tid = threadIdx.x, lane = tid & 63, wid = tid >> 6;
  int nb = xcd_swz(blockIdx.x, 1152);
  int m0 = (nb & 63)*128, s = nb >> 6;
  floatx4 acc[2][2] = {};
  const char*  Bsrc = (const char*)w1t + (size_t)s*32*1024;
  const float* Ags  = gs + ((size_t)(m0 + (tid>>1))*SS + s)*DD + (tid&1)*32;
  u16*         Gsb  = gsb + ((size_t)s*BB + m0 + (tid>>1))*DD + (tid&1)*32;   // (s,m,d)
  floatx4 fr[8];
  gstage<1>(Bsrc, 1024, 0, SMB+32768, wid, lane);
#pragma unroll
  for (int q=0;q<8;++q) fr[q] = *(const floatx4*)(Ags + q*4);
  for (int c=0;c<8;++c){
    char* Asc = SMB + (c&1)*16384;
    char* Bsc = SMB + 32768 + (c&1)*4096;
    { shortx8 v[4];
#pragma unroll
      for (int q=0;q<4;++q) v[q] = pack8v(fr[2*q], fr[2*q+1]);
      u16* gp = Gsb + c*64;
#pragma unroll
      for (int q=0;q<4;++q) *(shortx8*)(gp + q*8) = v[q];
      lds_store4(Asc, tid>>1, 128, (tid&1)*64, 7, v); }
    __syncthreads();
    int cn = c+1;
    if (cn < 8){
      gstage<1>(Bsrc, 1024, cn*128, SMB + 32768 + (cn&1)*4096, wid, lane);
      const float* p = Ags + cn*64;
#pragma unroll
      for (int q=0;q<8;++q) fr[q] = *(const floatx4*)(p + q*4);
    }
    mma64<2,2>(Asc, Bsc, wid*32, 0, lane, acc);
  }
  __syncthreads();
  char* G1  = SMB;
  char* W2s = SMB + 8192;
#pragma unroll
  for (int i=0;i<2;++i)
#pragma unroll
   for (int j=0;j<2;++j){
    int col = j*16 + (lane&15);
    float bias = b1[s*32 + col];
#pragma unroll
    for (int r=0;r<4;++r){
      int row = wid*32 + i*16 + ((lane>>4)<<2) + r;
      float v = fmaxf(acc[i][j][r] + bias, 0.f);
      int off = (row*64 + col*2) ^ ((row&3)<<4);
      *(u16*)(G1 + off) = f2bf(v);
    }
  }
  if (tid < 32){
    const u16* p = w2t + (size_t)s*32*32 + tid*32;
#pragma unroll
    for (int q=0;q<4;++q){
      int off = (tid*64 + q*16) ^ ((tid&3)<<4);
      *(shortx8*)(W2s + off) = *(const shortx8*)(p + q*8);
    }
  }
  __syncthreads();
  floatx4 acc2[2][2] = {};
  {
    shortx8 a[2], b[2];
#pragma unroll
    for (int i=0;i<2;++i) a[i] = lds_frag(G1,  wid*32 + i*16 + (lane&15), 64, 0, 3, lane);
#pragma unroll
    for (int j=0;j<2;++j) b[j] = lds_frag(W2s, j*16 + (lane&15),          64, 0, 3, lane);
#pragma unroll
    for (int i=0;i<2;++i)
#pragma unroll
      for (int j=0;j<2;++j)
        acc2[i][j] = __builtin_amdgcn_mfma_f32_16x16x32_bf16(a[i], b[j], acc2[i][j], 0,0,0);
  }
#pragma unroll
  for (int i=0;i<2;++i)
#pragma unroll
   for (int j=0;j<2;++j){
    int col = j*16 + (lane&15);
    float bias = b2[s*32 + col];
#pragma unroll
    for (int r=0;r<4;++r){
      int row = wid*32 + i*16 + ((lane>>4)<<2) + r;
      h2b[((size_t)(m0+row)*SS + s)*32 + col] = f2bf(acc2[i][j][r] + bias);
    }
  }
}

// ---------- gm + age (unchanged) ----------
__global__ __launch_bounds__(256) void k_gm(const u16* __restrict__ h2b,
     const u16* __restrict__ w1t, const u16* __restrict__ w2t,
     const float* __restrict__ b1, const float* __restrict__ b2,
     const float* __restrict__ ta, const float* __restrict__ aw1, const float* __restrict__ ab1,
     const float* __restrict__ aw2, const float* __restrict__ ab2,
     u16* __restrict__ gfab){
  __shared__ __align__(16) char As[128*128];
  __shared__ __align__(16) char Bs[128*128];
  __shared__ __align__(16) char G1[128*256];
  int tid=threadIdx.x, lane=tid&63, w=tid>>6;
  int m0 = blockIdx.x*128;
  floatx4 acc[2][8] = {};
  for (int c=0;c<9;++c){
    __syncthreads();
    stage_bf16(As, h2b + (size_t)m0*576 + c*64, 1152, tid);
    stage_bf16(Bs, w1t + c*64,                 1152, tid);
    __syncthreads();
    mma64<2,8>(As, Bs, w*32, 0, lane, acc);
  }
#pragma unroll
  for (int i=0;i<2;++i)
#pragma unroll
   for (int j=0;j<8;++j){
    int col = j*16 + (lane&15);
    float bias = b1[col];
#pragma unroll
    for (int r=0;r<4;++r){
      int row = w*32 + i*16 + ((lane>>4)<<2) + r;
      float v = fmaxf(acc[i][j][r] + bias, 0.f);
      int off = (row*256 + col*2) ^ ((row&7)<<4);
      *(u16*)(G1 + off) = f2bf(v);
    }
  }
  floatx4 acc2[2][8] = {};
  for (int c2=0;c2<2;++c2){
    __syncthreads();
    stage_bf16(Bs, w2t + c2*64, 256, tid);
    __syncthreads();
#pragma unroll
    for (int kk=0;kk<2;++kk){
      shortx8 a[2], b[8];
#pragma unroll
      for (int i=0;i<2;++i){
        int row = w*32 + i*16 + (lane&15);
        int off = (row*256 + c2*128 + kk*64 + ((lane>>4)<<4)) ^ ((row&7)<<4);
        a[i] = *(const shortx8*)(G1 + off);
      }
#pragma unroll
      for (int j=0;j<8;++j) b[j] = lds_frag(Bs, j*16 + (lane&15), 128, kk*64, 7, lane);
#pragma unroll
      for (int i=0;i<2;++i)
#pragma unroll
        for (int j=0;j<8;++j)
          acc2[i][j] = __builtin_amdgcn_mfma_f32_16x16x32_bf16(a[i], b[j], acc2[i][j], 0,0,0);
    }
  }
#pragma unroll
  for (int i=0;i<2;++i)
#pragma unroll
   for (int j=0;j<8;++j){
    int col = j*16 + (lane&15);
    float bias = b2[col];
#pragma unroll
    for (int r=0;r<4;++r){
      int row = w*32 + i*16 + ((lane>>4)<<2) + r;
      gfab[(size_t)(m0+row)*192 + col] = f2bf(acc2[i][j][r] + bias);
    }
  }
  if (tid < 128){
    int bidx = m0 + tid;
    float t = ta[bidx];
    float a1[16];
#pragma unroll
    for (int j2=0;j2<16;++j2){ float v = t*aw1[j2] + ab1[j2]; a1[j2] = fmaxf(v, 0.f); }
#pragma unroll
    for (int m=0;m<16;++m){
      float v = ab2[m];
#pragma unroll
      for (int j2=0;j2<16;++j2) v += a1[j2]*aw2[j2*16+m];
      gfab[(size_t)bidx*192 + 128 + m] = f2bf(v);
    }
    shortx8 zz = {};
#pragma unroll
    for (int z=0;z<6;++z) *(shortx8*)(gfab + (size_t)bidx*192 + 144 + z*8) = zz;
  }
}

// ---------- fc1: 128x128 tile, 8 waves, A direct->reg pipelined, B ring-3 in LDS ----------
__global__ __launch_bounds__(512, 4) void k_fc1(const u16* __restrict__ gfab,
     const u16* __restrict__ gsb, const u16* __restrict__ w1t,
     const float* __restrict__ b1, u16* __restrict__ y1b){
  __shared__ __align__(16) char SMB[49152];   // B ring 3x16KB; epilogue bounce 32KB
  int tid=threadIdx.x, lane=tid&63, wid=tid>>6;
  int nb = xcd_swz(blockIdx.x, 4608);
  int n2 = nb&3, m0 = ((nb>>2)&63)*128, s = nb>>8;
  int wm = (wid&3)*32, wn = (wid>>2)*64;
  floatx4 acc[2][4] = {};
  const char* pAg[2]; const char* pAs[2];
#pragma unroll
  for (int i=0;i<2;++i){
    int r = m0 + wm + 16*i + (lane&15);
    pAg[i] = (const char*)gfab + (size_t)r*384 + ((lane>>4)<<4);
    pAs[i] = (const char*)gsb + ((size_t)s*BB + r)*1024 + ((lane>>4)<<4);   // (s,m,d)
  }
  const char* gW = (const char*)w1t + ((size_t)s*512 + n2*128)*1408;
  shortx8 aA[2][2], aB[2][2];
#define LDA1(tc, A) do{ \
    if ((tc) < 3){ \
      A[0][0]=*(const shortx8*)(pAg[0]+(tc)*128);    A[0][1]=*(const shortx8*)(pAg[1]+(tc)*128); \
      A[1][0]=*(const shortx8*)(pAg[0]+(tc)*128+64); A[1][1]=*(const shortx8*)(pAg[1]+(tc)*128+64); \
    } else { \
      A[0][0]=*(const shortx8*)(pAs[0]+((tc)-3)*128);    A[0][1]=*(const shortx8*)(pAs[1]+((tc)-3)*128); \
      A[1][0]=*(const shortx8*)(pAs[0]+((tc)-3)*128+64); A[1][1]=*(const shortx8*)(pAs[1]+((tc)-3)*128+64); \
    } }while(0)
#define CHUNK1(c, ACUR, ANXT) do{ \
    if ((c)<10) asm volatile("s_waitcnt vmcnt(2)" ::: "memory"); \
    else        asm volatile("s_waitcnt vmcnt(0)" ::: "memory"); \
    __builtin_amdgcn_s_barrier(); \
    __builtin_amdgcn_sched_barrier(0); \
    if ((c)+1<11) LDA1((c)+1, ANXT); \
    __builtin_amdgcn_sched_barrier(0); \
    if ((c)+2<11) gstage8(gW, 1408, ((c)+2)*128, SMB + (((c)+2)%3)*16384, wid, lane); \
    __builtin_amdgcn_sched_barrier(0); \
    const char* Bb = SMB + ((c)%3)*16384; \
    _Pragma("unroll") \
    for (int kk=0;kk<2;++kk){ \
      shortx8 b[4]; \
      _Pragma("unroll") \
      for (int j=0;j<4;++j) b[j] = lds_frag(Bb, wn + j*16 + (lane&15), 128, kk*64, 7, lane); \
      __builtin_amdgcn_s_setprio(1); \
      _Pragma("unroll") \
      for (int i=0;i<2;++i) \
        _Pragma("unroll") \
        for (int j=0;j<4;++j) \
          acc[i][j] = __builtin_amdgcn_mfma_f32_16x16x32_bf16(ACUR[kk][i], b[j], acc[i][j], 0,0,0); \
      __builtin_amdgcn_s_setprio(0); \
    } }while(0)
  LDA1(0, aA);
  gstage8(gW, 1408, 0, SMB, wid, lane);
  gstage8(gW, 1408, 128, SMB+16384, wid, lane);
#pragma unroll
  for (int c=0;c<11;++c){
    if (c&1) CHUNK1(c, aB, aA); else CHUNK1(c, aA, aB);
  }
  __syncthreads();
  // epilogue: relu+bias -> SMB [128][256B] bf16 swizzled, then coalesced stores
#pragma unroll
  for (int i=0;i<2;++i)
#pragma unroll
   for (int j=0;j<4;++j){
    int col = wn + j*16 + (lane&15);
    float bias = b1[(size_t)s*512 + n2*128 + col];
#pragma unroll
    for (int r=0;r<4;++r){
      int row = wm + i*16 + ((lane>>4)<<2) + r;
      float v = fmaxf(acc[i][j][r] + bias, 0.f);
      int off = (row*256 + col*2) ^ ((row&7)<<4);
      *(u16*)(SMB + off) = f2bf(v);
    }
  }
  __syncthreads();
  {
    int row = tid>>2, q4 = tid&3;                          // 512 thr: 64B each
    u16* gp = y1b + ((size_t)s*BB + m0 + row)*DD + n2*128 + q4*32;   // (s,m,d)
#pragma unroll
    for (int q=0;q<4;++q){
      int off = (row*256 + q4*64 + q*16) ^ ((row&7)<<4);
      *(shortx8*)(gp + q*8) = *(const shortx8*)(SMB + off);
    }
  }
}

// ---------- fc2: 128x128 tile, 8 waves, A direct->reg pipelined, B ring-3 ----------
__global__ __launch_bounds__(512, 4) void k_fc2(const u16* __restrict__ y1b,
     const u16* __restrict__ gsb, const u16* __restrict__ w2t,
     const float* __restrict__ b2, float* __restrict__ out){
  __shared__ __align__(16) char SMB[49152];
  int tid=threadIdx.x, lane=tid&63, wid=tid>>6;
  int nb = xcd_swz(blockIdx.x, 4608);
  int n2 = nb&3, m0 = ((nb>>2)&63)*128, s = nb>>8;
  int wm = (wid&3)*32, wn = (wid>>2)*64;
  floatx4 acc[2][4] = {};
  const char* pA[2];
#pragma unroll
  for (int i=0;i<2;++i){
    int r = m0 + wm + 16*i + (lane&15);
    pA[i] = (const char*)y1b + ((size_t)s*BB + r)*1024 + ((lane>>4)<<4);    // (s,m,d)
  }
  const char* gW = (const char*)w2t + ((size_t)s*512 + n2*128)*1024;
  shortx8 aA[2][2], aB[2][2];
#define LDA2(tc, A) do{ \
    A[0][0]=*(const shortx8*)(pA[0]+(tc)*128);    A[0][1]=*(const shortx8*)(pA[1]+(tc)*128); \
    A[1][0]=*(const shortx8*)(pA[0]+(tc)*128+64); A[1][1]=*(const shortx8*)(pA[1]+(tc)*128+64); \
  }while(0)
#define CHUNK2(c, ACUR, ANXT) do{ \
    if ((c)<7) asm volatile("s_waitcnt vmcnt(2)" ::: "memory"); \
    else       asm volatile("s_waitcnt vmcnt(0)" ::: "memory"); \
    __builtin_amdgcn_s_barrier(); \
    __builtin_amdgcn_sched_barrier(0); \
    if ((c)+1<8) LDA2((c)+1, ANXT); \
    __builtin_amdgcn_sched_barrier(0); \
    if ((c)+2<8) gstage8(gW, 1024, ((c)+2)*128, SMB + (((c)+2)%3)*16384, wid, lane); \
    __builtin_amdgcn_sched_barrier(0); \
    const char* Bb = SMB + ((c)%3)*16384; \
    _Pragma("unroll") \
    for (int kk=0;kk<2;++kk){ \
      shortx8 b[4]; \
      _Pragma("unroll") \
      for (int j=0;j<4;++j) b[j] = lds_frag(Bb, wn + j*16 + (lane&15), 128, kk*64, 7, lane); \
      __builtin_amdgcn_s_setprio(1); \
      _Pragma("unroll") \
      for (int i=0;i<2;++i) \
        _Pragma("unroll") \
        for (int j=0;j<4;++j) \
          acc[i][j] = __builtin_amdgcn_mfma_f32_16x16x32_bf16(ACUR[kk][i], b[j], acc[i][j], 0,0,0); \
      __builtin_amdgcn_s_setprio(0); \
    } }while(0)
  LDA2(0, aA);
  gstage8(gW, 1024, 0, SMB, wid, lane);
  gstage8(gW, 1024, 128, SMB+16384, wid, lane);
#pragma unroll
  for (int c=0;c<8;++c){
    if (c&1) CHUNK2(c, aB, aA); else CHUNK2(c, aA, aB);
  }
  // epilogue: two m-halves via fp32 LDS [64][512B] (32KB), then coalesced out-stores
  float* SMF = (float*)SMB;
#pragma unroll 1
  for (int h=0;h<2;++h){
    __syncthreads();
    if (((wid&3)>>1) == h){
#pragma unroll
      for (int i=0;i<2;++i)
#pragma unroll
       for (int j=0;j<4;++j){
        int col = wn + j*16 + (lane&15);
#pragma unroll
        for (int r=0;r<4;++r){
          int rl = ((wid&1)*32) + i*16 + ((lane>>4)<<2) + r;   // row within half
          int off = (rl*512 + col*4) ^ ((rl&7)<<4);
          *(float*)((char*)SMF + off) = acc[i][j][r];
        }
      }
    }
    __syncthreads();
    {
      int rl = tid>>3, e8 = tid&7;                      // 512 thr: 64B (16 floats) each
      int grow = m0 + h*64 + rl;
      size_t gidx = ((size_t)grow*SS + s)*DD + n2*128 + e8*16;          // out: (m,s,d)
      const float* bp = b2 + (size_t)s*512 + n2*128 + e8*16;
      const u16*   gp = gsb + ((size_t)s*BB + grow)*DD + n2*128 + e8*16; // gsb: (s,m,d)
      shortx8 gv[2];
      gv[0] = *(const shortx8*)(gp);
      gv[1] = *(const shortx8*)(gp + 8);
#pragma unroll
      for (int q=0;q<4;++q){
        int off = (rl*512 + e8*64 + q*16) ^ ((rl&7)<<4);
        floatx4 v = *(const floatx4*)((char*)SMF + off);
        floatx4 bb = *(const floatx4*)(bp + q*4);
        floatx4 g;
        g[0]=bf2f((u16)gv[q>>1][(q&1)*4+0]); g[1]=bf2f((u16)gv[q>>1][(q&1)*4+1]);
        g[2]=bf2f((u16)gv[q>>1][(q&1)*4+2]); g[3]=bf2f((u16)gv[q>>1][(q&1)*4+3]);
        *(floatx4*)(out + gidx + q*4) = v + bb + g;
      }
    }
  }
}

// ---------- launch ----------
extern "C" void kernel_launch(void* const* d_in, const int* in_sizes, int n_in,
                              void* d_out, int out_size, void* d_ws, size_t ws_size,
                              hipStream_t stream){
  (void)in_sizes; (void)n_in; (void)out_size; (void)ws_size;
  const float* gs   = (const float*)d_in[1];
  const float* ta   = (const float*)d_in[2];
  const float* bnw1 = (const float*)d_in[3];
  const float* bnb1 = (const float*)d_in[4];
  const float* bnw2 = (const float*)d_in[5];
  const float* bnb2 = (const float*)d_in[6];
  const float* gmw1 = (const float*)d_in[7];
  const float* gmb1 = (const float*)d_in[8];
  const float* gmw2 = (const float*)d_in[9];
  const float* gmb2 = (const float*)d_in[10];
  const float* aw1  = (const float*)d_in[11];
  const float* ab1  = (const float*)d_in[12];
  const float* aw2  = (const float*)d_in[13];
  const float* ab2  = (const float*)d_in[14];
  const float* fcw1 = (const float*)d_in[15];
  const float* fcb1 = (const float*)d_in[16];
  const float* fcw2 = (const float*)d_in[17];
  const float* fcb2 = (const float*)d_in[18];

  char* ws = (char*)d_ws;
  u16* fcW1t = (u16*)(ws + 0);                  // 12,976,128
  u16* fcW2t = (u16*)(ws + 12976128);           //  9,437,184
  u16* bnW1t = (u16*)(ws + 22413312);           //    589,824
  u16* bnW2t = (u16*)(ws + 23003136);           //     36,864
  u16* gmW1t = (u16*)(ws + 23040000);           //    147,456
  u16* gmW2t = (u16*)(ws + 23187456);           //     32,768
  u16* h2b   = (u16*)(ws + 23220224);           //  9,437,184
  u16* gfab  = (u16*)(ws + 32657408);           //  3,145,728 (B x 192)
  u16* y1b   = (u16*)(ws + 35803136);           // 150,994,944  (s,m,d)
  u16* gsb   = (u16*)(ws + 186798080);          // 150,994,944  (s,m,d)
  float* out = (float*)d_out;

  dim3 blk(256);
  transpose_w2<<<dim3(16,1,18),  blk, 0, stream>>>(bnw1, bnW1t, 512, 0, 512,  32, 512, 0);
  transpose_w2<<<dim3(1,1,18),   blk, 0, stream>>>(bnw2, bnW2t,  32, 0,  32,  32,  32, 0);
  transpose_w2<<<dim3(18,4,1),   blk, 0, stream>>>(gmw1, gmW1t, 576, 0, 576, 128, 576, 0);
  transpose_w2<<<dim3(4,4,1),    blk, 0, stream>>>(gmw2, gmW2t, 128, 0, 128, 128, 128, 0);
  transpose_w2<<<dim3(6,16,18),  blk, 0, stream>>>(fcw1, fcW1t, 656, 0,   144, 512, 704, 0);
  transpose_w2<<<dim3(16,16,18), blk, 0, stream>>>(fcw1, fcW1t, 656, 144, 512, 512, 704, 192);
  transpose_w2<<<dim3(16,16,18), blk, 0, stream>>>(fcw2, fcW2t, 512, 0, 512, 512, 512, 0);

  k_bn <<<dim3(1152), blk,       0, stream>>>(gs, bnW1t, bnW2t, bnb1, bnb2, h2b, gsb);
  k_gm <<<dim3(64),   blk,       0, stream>>>(h2b, gmW1t, gmW2t, gmb1, gmb2, ta, aw1, ab1, aw2, ab2, gfab);
  k_fc1<<<dim3(4608), dim3(512), 0, stream>>>(gfab, gsb, fcW1t, fcb1, y1b);
  k_fc2<<<dim3(4608), dim3(512), 0, stream>>>(y1b, gsb, fcW2t, fcb2, out);
}